// Round 15
// baseline (243.955 us; speedup 1.0000x reference)
//
#include <hip/hip_runtime.h>
#include <stdint.h>
#include <math.h>

// ---------------- workspace layout (bytes) ----------------
#define OFF_T2     3712      // int[64]
#define OFF_T3     4224      // int[128]
#define OFF_T4     5248      // int[256]
#define OFF_W2     7296      // uint32[64*9]
#define OFF_W3     9600      // uint64[128*9]
#define OFF_W4     18816     // uint64[256*9*2]  (16B aligned)
#define OFF_A1     55680     // uint32[32*224*224]   6,422,528 B
#define OFF_A2     6478208   // uint64[32*112*112]   3,211,264 B
#define OFF_A3     9689472   // uint64[2][32*56*56]  1,605,632 B (planar)
#define OFF_CNT    11295104  // int[32*256] (ARR contiguous after)
#define OFF_ARR    11327872  // int[32]

#define C2_LW 116

// BN(x) >= 0 decided exactly as np fp32 would: fl(fl(x*sc)+sh) >= 0
static __device__ __forceinline__ float2 bnf(float g, float b, float m, float v) {
    float sc = __fdiv_rn(g, __fsqrt_rn(__fadd_rn(v, 1e-5f)));
    float sh = __fsub_rn(b, __fmul_rn(m, sc));
    return make_float2(sc, sh);
}
static __device__ __forceinline__ bool bnpos(float s, float2 p) {
    return __fadd_rn(__fmul_rn(s, p.x), p.y) >= 0.0f;
}
// minimal EVEN integer s with bnpos((float)s) true (monotone, sc>0); K+2 = never
static __device__ __forceinline__ int find_T(int K, float2 p) {
    int lo = -K - 2, hi = K + 2;
    while (lo + 2 < hi) {
        int mid = ((lo + hi) >> 1) & ~1;
        if (bnpos((float)mid, p)) hi = mid; else lo = mid;
    }
    return hi;
}

#define CONV1_BLOCKS 1568   // 401408 quads (4px each) / 256
#define PREP_BLOCKS  1619   // (6344 wave-tasks*64 + 8224 zero ints) / 256, ceil

// ========== fused front: conv1 (4px, og-tiled acc, R14-proven) + prep + CNT/ARR zero ==========
__global__ __launch_bounds__(256) void k_front(
    const float* __restrict__ x, const float* __restrict__ w1,
    const float* __restrict__ g1, const float* __restrict__ b1,
    const float* __restrict__ m1, const float* __restrict__ v1,
    const float* __restrict__ w2, const float* __restrict__ w3, const float* __restrict__ w4,
    const float* g2, const float* b2, const float* m2, const float* v2,
    const float* g3, const float* b3, const float* m3, const float* v3,
    const float* g4, const float* b4, const float* m4, const float* v4,
    uint32_t* __restrict__ A1,
    int* __restrict__ T2, int* __restrict__ T3, int* __restrict__ T4,
    uint32_t* __restrict__ W2, uint64_t* __restrict__ W3, uint64_t* __restrict__ W4,
    int* __restrict__ Z /* CNT..ARR contiguous, 8224 ints */)
{
    int tid = threadIdx.x;
    if (blockIdx.x >= CONV1_BLOCKS) {
        // ---------------- prep region (R9/R12-proven) ----------------
        int gtid = (blockIdx.x - CONV1_BLOCKS) * 256 + tid;
        int wid  = gtid >> 6;
        int lane = gtid & 63;
        if (wid < 576) {
            int oc = wid / 9, t = wid - oc * 9;
            float v = (lane < 32) ? w2[oc * 288 + lane * 9 + t] : -1.0f;
            uint64_t m = __ballot(v >= 0.0f);
            if (lane == 0) W2[wid] = (uint32_t)m;
        } else if (wid < 1728) {
            int i = wid - 576;
            int oc = i / 9, t = i - oc * 9;
            float v = w3[oc * 576 + lane * 9 + t];
            uint64_t m = __ballot(v >= 0.0f);
            if (lane == 0) W3[i] = m;
        } else if (wid < 6336) {
            int i = wid - 1728;
            int oc = i / 18, rem = i - oc * 18;
            int t = rem >> 1, h = rem & 1;
            float v = w4[oc * 1152 + (h * 64 + lane) * 9 + t];
            uint64_t m = __ballot(v >= 0.0f);
            if (lane == 0) W4[i] = m;
        } else if (wid < 6344) {
            int c = (wid - 6336) * 64 + lane;   // 0..511
            if (c < 64) {
                T2[c] = find_T(288, bnf(g2[c], b2[c], m2[c], v2[c]));
            } else if (c < 192) {
                int cc = c - 64;
                T3[cc] = find_T(576, bnf(g3[cc], b3[cc], m3[cc], v3[cc]));
            } else if (c < 448) {
                int cc = c - 192;
                T4[cc] = find_T(1152, bnf(g4[cc], b4[cc], m4[cc], v4[cc]));
            }
        } else {
            int zi = gtid - 406016;
            if (zi < 8224) Z[zi] = 0;   // CNT[8192] + ARR[32]
        }
        return;
    }

    // ---------------- conv1: 4 px/thread, oc-group-tiled accumulators ----------------
    __shared__ float  wl[27 * 32];   // [k][oc]
    __shared__ float2 s1[32];
    for (int i = tid; i < 864; i += 256) {
        int k = i >> 5, oc = i & 31;
        wl[i] = w1[oc * 27 + k];
    }
    if (tid < 32) s1[tid] = bnf(g1[tid], b1[tid], m1[tid], v1[tid]);
    __syncthreads();

    int q  = blockIdx.x * 256 + tid;    // quad id: [b][y][xq]
    int xq = q % 56;
    int t  = q / 56;
    int y  = t % 224;
    int b  = t / 224;
    int xc = xq * 4;

    const float* xb = x + (size_t)b * 150528;
    bool interior = ((unsigned)(y - 1) < 222u) && ((unsigned)(xq - 1) < 54u);

    float xin[9][6];
    #pragma unroll
    for (int ic = 0; ic < 3; ic++)
        #pragma unroll
        for (int ky = 0; ky < 3; ky++) {
            int iy = y - 1 + ky;
            const float* rp = xb + ic * 50176 + iy * 224 + (xc - 1);
            float* xr = xin[ic * 3 + ky];
            if (interior) {
                #pragma unroll
                for (int c = 0; c < 6; c++) xr[c] = rp[c];
            } else {
                #pragma unroll
                for (int c = 0; c < 6; c++) {
                    int ix = xc - 1 + c;
                    xr[c] = ((unsigned)iy < 224u && (unsigned)ix < 224u) ? rp[c] : 0.0f;
                }
            }
        }

    const float4* wl4 = (const float4*)wl;
    uint32_t bits0 = 0, bits1 = 0, bits2 = 0, bits3 = 0;

    #pragma unroll 1                     // keep og live-set small: acc[4][4] only
    for (int og = 0; og < 8; og++) {
        float acc[4][4];
        #pragma unroll
        for (int px = 0; px < 4; px++)
            #pragma unroll
            for (int j = 0; j < 4; j++) acc[px][j] = 0.0f;

        #pragma unroll
        for (int k = 0; k < 27; k++) {   // k-ascending per acc chain: bit-exact
            float4 w = wl4[k * 8 + og];
            int row = k / 3, kx = k % 3;
            #pragma unroll
            for (int px = 0; px < 4; px++) {
                float a = xin[row][kx + px];
                acc[px][0] = fmaf(a, w.x, acc[px][0]);
                acc[px][1] = fmaf(a, w.y, acc[px][1]);
                acc[px][2] = fmaf(a, w.z, acc[px][2]);
                acc[px][3] = fmaf(a, w.w, acc[px][3]);
            }
        }

        #pragma unroll
        for (int j = 0; j < 4; j++) {
            float2 p = s1[og * 4 + j];
            int sh = og * 4 + j;
            bits0 |= (uint32_t)bnpos(acc[0][j], p) << sh;
            bits1 |= (uint32_t)bnpos(acc[1][j], p) << sh;
            bits2 |= (uint32_t)bnpos(acc[2][j], p) << sh;
            bits3 |= (uint32_t)bnpos(acc[3][j], p) << sh;
        }
    }

    uint4* dst = (uint4*)(A1 + (size_t)b * 50176 + y * 224 + xc);  // 16B aligned
    *dst = make_uint4(bits0, bits1, bits2, bits3);
}

// ======== conv2 (R9-proven, verbatim) ========
template<unsigned VM>
static __device__ __forceinline__ bool pred2(const uint32_t (&w)[3][9], int j,
                                             const uint32_t (&wr)[9], int T) {
    int pc = 0;
    #pragma unroll
    for (int ky = 0; ky < 3; ky++)
        #pragma unroll
        for (int kx = 0; kx < 3; kx++) {
            int ti = ky * 3 + kx;
            if (VM & (1u << ti)) pc += __popc(w[ky][2 * j + kx] ^ wr[ti]);
        }
    constexpr int nv = __builtin_popcount(VM);
    return pc <= ((32 * nv - T) >> 1);
}

template<unsigned VM0, unsigned VM>
static __device__ __forceinline__ void group2(const uint32_t* lrow, int g,
        const uint32_t (&wr)[9], int T, uint64_t* dst, int lane) {
    uint32_t win[3][9];
    int c0 = 8 * g;
    #pragma unroll
    for (int r = 0; r < 3; r++) {
        const uint32_t* rp = lrow + r * C2_LW + c0;
        uint4 a = *(const uint4*)(rp);
        uint4 b = *(const uint4*)(rp + 4);
        win[r][0] = a.x; win[r][1] = a.y; win[r][2] = a.z; win[r][3] = a.w;
        win[r][4] = b.x; win[r][5] = b.y; win[r][6] = b.z; win[r][7] = b.w;
        win[r][8] = rp[8];
    }
    uint64_t b0 = __ballot(pred2<VM0>(win, 0, wr, T));
    uint64_t b1 = __ballot(pred2<VM >(win, 1, wr, T));
    uint64_t b2 = __ballot(pred2<VM >(win, 2, wr, T));
    uint64_t b3 = __ballot(pred2<VM >(win, 3, wr, T));
    if (lane == 0) {
        ulonglong2* d = (ulonglong2*)(dst + 4 * g);
        d[0] = make_ulonglong2(b0, b1);
        d[1] = make_ulonglong2(b2, b3);
    }
}

__global__ __launch_bounds__(256) void k_conv2(
    const uint32_t* __restrict__ A1, const uint32_t* __restrict__ W2g,
    const int* __restrict__ T2, uint64_t* __restrict__ A2)
{
    __shared__ __align__(16) uint32_t lds[9 * C2_LW];
    int bi = blockIdx.x;
    int b = bi / 56, rem = bi % 56;
    int oyq = rem >> 1, h = rem & 1;
    int xs = h * 56;
    int tid = threadIdx.x;
    const uint32_t* ap = A1 + (size_t)b * 50176;
    for (int i = tid; i < 9 * C2_LW; i += 256) {
        int r = i / C2_LW, c = i - r * C2_LW;
        int iy = oyq * 8 - 1 + r, ix = 2 * xs - 1 + c;
        uint32_t v = 0;
        if ((unsigned)iy < 224u && (unsigned)ix < 224u) v = ap[iy * 224 + ix];
        lds[i] = v;
    }
    __syncthreads();

    int w = tid >> 6, lane = tid & 63;
    int oy = oyq * 4 + w;
    uint32_t wr[9];
    #pragma unroll
    for (int ti = 0; ti < 9; ti++) wr[ti] = W2g[lane * 9 + ti];
    int T = T2[lane];
    const uint32_t* lrow = lds + 2 * w * C2_LW;
    uint64_t* dst = A2 + (size_t)b * 12544 + oy * 112 + xs;
    bool left = (xs == 0);

    if (oy == 0) {
        if (left) group2<0x1B0, 0x1F8>(lrow, 0, wr, T, dst, lane);
        else      group2<0x1F8, 0x1F8>(lrow, 0, wr, T, dst, lane);
        for (int g = 1; g < 14; g++) group2<0x1F8, 0x1F8>(lrow, g, wr, T, dst, lane);
    } else {
        if (left) group2<0x1B6, 0x1FF>(lrow, 0, wr, T, dst, lane);
        else      group2<0x1FF, 0x1FF>(lrow, 0, wr, T, dst, lane);
        for (int g = 1; g < 14; g++) group2<0x1FF, 0x1FF>(lrow, g, wr, T, dst, lane);
    }
}

// ======== conv3 (R9-proven, verbatim): A2 -> A3 planar [2][32][56][56] ========
#define C3_LW 58
template<unsigned VM>
static __device__ __forceinline__ bool pred3(const uint64_t (&w)[3][9], int j,
                                             const uint64_t (&wr)[9], int T) {
    int pc = 0;
    #pragma unroll
    for (int ky = 0; ky < 3; ky++)
        #pragma unroll
        for (int kx = 0; kx < 3; kx++) {
            int ti = ky * 3 + kx;
            if (VM & (1u << ti)) pc += __popcll(w[ky][2 * j + kx] ^ wr[ti]);
        }
    constexpr int nv = __builtin_popcount(VM);
    return pc <= ((64 * nv - T) >> 1);
}

template<unsigned VM0, unsigned VM>
static __device__ __forceinline__ void group3(const uint64_t* lrow, int g,
        const uint64_t (&wr)[9], int T, uint64_t* dst, int lane) {
    uint64_t win[3][9];
    int c0 = 8 * g;
    #pragma unroll
    for (int r = 0; r < 3; r++) {
        const uint64_t* rp = lrow + r * C3_LW + c0;
        ulonglong2 a0 = *(const ulonglong2*)(rp);
        ulonglong2 a1 = *(const ulonglong2*)(rp + 2);
        ulonglong2 a2 = *(const ulonglong2*)(rp + 4);
        ulonglong2 a3 = *(const ulonglong2*)(rp + 6);
        win[r][0] = a0.x; win[r][1] = a0.y; win[r][2] = a1.x; win[r][3] = a1.y;
        win[r][4] = a2.x; win[r][5] = a2.y; win[r][6] = a3.x; win[r][7] = a3.y;
        win[r][8] = rp[8];
    }
    uint64_t b0 = __ballot(pred3<VM0>(win, 0, wr, T));
    uint64_t b1 = __ballot(pred3<VM >(win, 1, wr, T));
    uint64_t b2 = __ballot(pred3<VM >(win, 2, wr, T));
    uint64_t b3 = __ballot(pred3<VM >(win, 3, wr, T));
    if (lane == 0) {
        ulonglong2* d = (ulonglong2*)(dst + 4 * g);
        d[0] = make_ulonglong2(b0, b1);
        d[1] = make_ulonglong2(b2, b3);
    }
}

__global__ __launch_bounds__(256) void k_conv3(
    const uint64_t* __restrict__ A2, const uint64_t* __restrict__ W3g,
    const int* __restrict__ T3, uint64_t* __restrict__ A3)
{
    __shared__ __align__(16) uint64_t lds[5 * C3_LW];
    int bi = blockIdx.x;
    int b = bi / 56, rem = bi % 56;
    int oyp = rem >> 1, h = rem & 1;
    int xs = h * 28;
    int tid = threadIdx.x;
    const uint64_t* ap = A2 + (size_t)b * 12544;
    for (int i = tid; i < 5 * C3_LW; i += 256) {
        int r = i / C3_LW, c = i - r * C3_LW;
        int iy = oyp * 4 - 1 + r, ix = 2 * xs - 1 + c;
        uint64_t v = 0;
        if ((unsigned)iy < 112u && (unsigned)ix < 112u) v = ap[iy * 112 + ix];
        lds[i] = v;
    }
    __syncthreads();

    int w = tid >> 6, lane = tid & 63;
    int oy = oyp * 2 + (w >> 1);
    int g  = w & 1;
    int oc = g * 64 + lane;
    uint64_t wr[9];
    #pragma unroll
    for (int ti = 0; ti < 9; ti++) wr[ti] = W3g[oc * 9 + ti];
    int T = T3[oc];
    const uint64_t* lrow = lds + 2 * (w >> 1) * C3_LW;
    uint64_t* dst = A3 + (size_t)g * 100352 + (size_t)b * 3136 + oy * 56 + xs;
    bool left = (xs == 0);

    if (oy == 0) {
        if (left) group3<0x1B0, 0x1F8>(lrow, 0, wr, T, dst, lane);
        else      group3<0x1F8, 0x1F8>(lrow, 0, wr, T, dst, lane);
        for (int gg = 1; gg < 7; gg++) group3<0x1F8, 0x1F8>(lrow, gg, wr, T, dst, lane);
    } else {
        if (left) group3<0x1B6, 0x1FF>(lrow, 0, wr, T, dst, lane);
        else      group3<0x1FF, 0x1FF>(lrow, 0, wr, T, dst, lane);
        for (int gg = 1; gg < 7; gg++) group3<0x1FF, 0x1FF>(lrow, gg, wr, T, dst, lane);
    }
}

// ======== conv4 -> CNT + ARR-triggered fc (bodies R9/R12-proven) ========
template<unsigned VM>
static __device__ __forceinline__ bool pred4(const uint64_t (&w0)[3][5],
                                             const uint64_t (&w1)[3][5], int j,
                                             const ulonglong2 (&wr)[9], int T) {
    int pc = 0;
    #pragma unroll
    for (int ky = 0; ky < 3; ky++)
        #pragma unroll
        for (int kx = 0; kx < 3; kx++) {
            int ti = ky * 3 + kx;
            if (VM & (1u << ti)) {
                pc += __popcll(w0[ky][2 * j + kx] ^ wr[ti].x);
                pc += __popcll(w1[ky][2 * j + kx] ^ wr[ti].y);
            }
        }
    constexpr int nv = __builtin_popcount(VM);
    return pc <= ((128 * nv - T) >> 1);
}

template<unsigned VM0, unsigned VM>
static __device__ __forceinline__ int group4c(const uint64_t* ldsb, int g,
        const ulonglong2 (&wr)[9], int T) {
    uint64_t w0[3][5], w1[3][5];
    int c0 = 4 * g;
    #pragma unroll
    for (int r = 0; r < 3; r++) {
        const uint64_t* rp0 = ldsb + r * 30 + c0;
        const uint64_t* rp1 = ldsb + (3 + r) * 30 + c0;
        ulonglong2 a0 = *(const ulonglong2*)(rp0);
        ulonglong2 a1 = *(const ulonglong2*)(rp0 + 2);
        w0[r][0] = a0.x; w0[r][1] = a0.y; w0[r][2] = a1.x; w0[r][3] = a1.y;
        w0[r][4] = rp0[4];
        ulonglong2 b0 = *(const ulonglong2*)(rp1);
        ulonglong2 b1 = *(const ulonglong2*)(rp1 + 2);
        w1[r][0] = b0.x; w1[r][1] = b0.y; w1[r][2] = b1.x; w1[r][3] = b1.y;
        w1[r][4] = rp1[4];
    }
    int c = 0;
    c += pred4<VM0>(w0, w1, 0, wr, T) ? 1 : 0;
    c += pred4<VM >(w0, w1, 1, wr, T) ? 1 : 0;
    return c;
}

__global__ __launch_bounds__(256) void k_conv4(
    const uint64_t* __restrict__ A3, const uint64_t* __restrict__ W4g,
    const int* __restrict__ T4, int* __restrict__ CNT, int* __restrict__ ARR,
    const float* __restrict__ fcw, const float* __restrict__ fcb,
    float* __restrict__ out)
{
    __shared__ __align__(16) uint64_t lds[2 * 3 * 30];
    __shared__ double r0[256], r1[256];
    __shared__ int flag;
    int bi = blockIdx.x;
    int b = bi / 56, rem = bi % 56;
    int oy = rem >> 1, h = rem & 1;
    int tid = threadIdx.x;
    const uint64_t* ap = A3 + (size_t)b * 3136;
    for (int i = tid; i < 174; i += 256) {
        int p = i / 87, j = i - p * 87;
        int r = j / 29, c = j - r * 29;
        int iy = 2 * oy - 1 + r, ix = 2 * h * 14 - 1 + c;
        uint64_t v = 0;
        if ((unsigned)iy < 56u && (unsigned)ix < 56u)
            v = ap[(size_t)p * 100352 + iy * 56 + ix];
        lds[(p * 3 + r) * 30 + c] = v;
    }
    __syncthreads();

    int w = tid >> 6, lane = tid & 63;
    int oc = w * 64 + lane;
    ulonglong2 wr[9];
    const ulonglong2* wp = (const ulonglong2*)(W4g + oc * 18);
    #pragma unroll
    for (int ti = 0; ti < 9; ti++) wr[ti] = wp[ti];
    int T = T4[oc];
    bool left = (h == 0);

    int cnt = 0;
    if (oy == 0) {
        if (left) cnt += group4c<0x1B0, 0x1F8>(lds, 0, wr, T);
        else      cnt += group4c<0x1F8, 0x1F8>(lds, 0, wr, T);
        for (int g = 1; g < 7; g++) cnt += group4c<0x1F8, 0x1F8>(lds, g, wr, T);
    } else {
        if (left) cnt += group4c<0x1B6, 0x1FF>(lds, 0, wr, T);
        else      cnt += group4c<0x1FF, 0x1FF>(lds, 0, wr, T);
        for (int g = 1; g < 7; g++) cnt += group4c<0x1FF, 0x1FF>(lds, g, wr, T);
    }
    atomicAdd(&CNT[b * 256 + oc], cnt);

    // ---- 56th-arriving block per image does mean + fc (R11/R12-proven pattern) ----
    __syncthreads();
    if (tid == 0) {
        __threadfence();
        flag = atomicAdd(&ARR[b], 1);
    }
    __syncthreads();
    if (flag == 55) {
        __threadfence();
        int c2 = atomicAdd(&CNT[b * 256 + tid], 0);   // coherent read
        double mean = (2.0 * (double)c2 - 784.0) * (1.0 / 784.0);
        r0[tid] = (double)fcw[tid]       * mean;
        r1[tid] = (double)fcw[256 + tid] * mean;
        __syncthreads();
        for (int s = 128; s > 0; s >>= 1) {
            if (tid < s) { r0[tid] += r0[tid + s]; r1[tid] += r1[tid + s]; }
            __syncthreads();
        }
        if (tid == 0) {
            out[b * 2 + 0] = (float)(r0[0] + (double)fcb[0]);
            out[b * 2 + 1] = (float)(r1[0] + (double)fcb[1]);
        }
    }
}

extern "C" void kernel_launch(void* const* d_in, const int* in_sizes, int n_in,
                              void* d_out, int out_size, void* d_ws, size_t ws_size,
                              hipStream_t stream) {
    const float* x   = (const float*)d_in[0];
    const float* w1  = (const float*)d_in[1];
    const float* w2  = (const float*)d_in[2];
    const float* w3  = (const float*)d_in[3];
    const float* w4  = (const float*)d_in[4];
    const float* g1 = (const float*)d_in[5],  *b1 = (const float*)d_in[6],
               * m1 = (const float*)d_in[7],  *v1 = (const float*)d_in[8];
    const float* g2 = (const float*)d_in[9],  *b2 = (const float*)d_in[10],
               * m2 = (const float*)d_in[11], *v2 = (const float*)d_in[12];
    const float* g3 = (const float*)d_in[13], *b3 = (const float*)d_in[14],
               * m3 = (const float*)d_in[15], *v3 = (const float*)d_in[16];
    const float* g4 = (const float*)d_in[17], *b4 = (const float*)d_in[18],
               * m4 = (const float*)d_in[19], *v4 = (const float*)d_in[20];
    const float* fcw = (const float*)d_in[21];
    const float* fcb = (const float*)d_in[22];
    float* out = (float*)d_out;

    char* ws = (char*)d_ws;
    int*      T2  = (int*)(ws + OFF_T2);
    int*      T3  = (int*)(ws + OFF_T3);
    int*      T4  = (int*)(ws + OFF_T4);
    uint32_t* W2  = (uint32_t*)(ws + OFF_W2);
    uint64_t* W3  = (uint64_t*)(ws + OFF_W3);
    uint64_t* W4  = (uint64_t*)(ws + OFF_W4);
    uint32_t* A1  = (uint32_t*)(ws + OFF_A1);
    uint64_t* A2  = (uint64_t*)(ws + OFF_A2);
    uint64_t* A3  = (uint64_t*)(ws + OFF_A3);
    int*      CNT = (int*)(ws + OFF_CNT);
    int*      ARR = (int*)(ws + OFF_ARR);

    hipLaunchKernelGGL(k_front, dim3(CONV1_BLOCKS + PREP_BLOCKS), dim3(256), 0, stream,
                       x, w1, g1, b1, m1, v1, w2, w3, w4,
                       g2, b2, m2, v2, g3, b3, m3, v3, g4, b4, m4, v4,
                       A1, T2, T3, T4, W2, W3, W4, CNT);
    hipLaunchKernelGGL(k_conv2, dim3(1792), dim3(256), 0, stream, A1, W2, T2, A2);
    hipLaunchKernelGGL(k_conv3, dim3(1792), dim3(256), 0, stream, A2, W3, T3, A3);
    hipLaunchKernelGGL(k_conv4, dim3(1792), dim3(256), 0, stream,
                       A3, W4, T4, CNT, ARR, fcw, fcb, out);
}

// Round 16
// 215.490 us; speedup vs baseline: 1.1321x; 1.1321x over previous
//
#include <hip/hip_runtime.h>
#include <stdint.h>
#include <math.h>

// ---------------- workspace layout (bytes) ----------------
#define OFF_T2     3712      // int[64]
#define OFF_T3     4224      // int[128]
#define OFF_T4     5248      // int[256]
#define OFF_W2     7296      // uint32[64*9]
#define OFF_W3     9600      // uint64[128*9]
#define OFF_W4     18816     // uint64[256*9*2]  (16B aligned)
#define OFF_A1     55680     // uint32[32*224*224]   6,422,528 B
#define OFF_A2     6478208   // uint64[32*112*112]   3,211,264 B
#define OFF_A3     9689472   // uint64[2][32*56*56]  1,605,632 B (planar)
#define OFF_CNT    11295104  // int[32*256]             32,768 B

#define C2_LW 116

// BN(x) >= 0 decided exactly as np fp32 would: fl(fl(x*sc)+sh) >= 0
static __device__ __forceinline__ float2 bnf(float g, float b, float m, float v) {
    float sc = __fdiv_rn(g, __fsqrt_rn(__fadd_rn(v, 1e-5f)));
    float sh = __fsub_rn(b, __fmul_rn(m, sc));
    return make_float2(sc, sh);
}
static __device__ __forceinline__ bool bnpos(float s, float2 p) {
    return __fadd_rn(__fmul_rn(s, p.x), p.y) >= 0.0f;
}
// minimal EVEN integer s with bnpos((float)s) true (monotone, sc>0); K+2 = never
static __device__ __forceinline__ int find_T(int K, float2 p) {
    int lo = -K - 2, hi = K + 2;
    while (lo + 2 < hi) {
        int mid = ((lo + hi) >> 1) & ~1;
        if (bnpos((float)mid, p)) hi = mid; else lo = mid;
    }
    return hi;
}

#define CONV1_BLOCKS 1568   // 401408 quads (4px each) / 256
#define PREP_BLOCKS  1618   // (6344 wave-tasks*64 + 8192 zero ints) / 256

// ========== fused front: conv1 (4px, og-tiled acc) + prep + CNT zero ==========
__global__ __launch_bounds__(256) void k_front(
    const float* __restrict__ x, const float* __restrict__ w1,
    const float* __restrict__ g1, const float* __restrict__ b1,
    const float* __restrict__ m1, const float* __restrict__ v1,
    const float* __restrict__ w2, const float* __restrict__ w3, const float* __restrict__ w4,
    const float* g2, const float* b2, const float* m2, const float* v2,
    const float* g3, const float* b3, const float* m3, const float* v3,
    const float* g4, const float* b4, const float* m4, const float* v4,
    uint32_t* __restrict__ A1,
    int* __restrict__ T2, int* __restrict__ T3, int* __restrict__ T4,
    uint32_t* __restrict__ W2, uint64_t* __restrict__ W3, uint64_t* __restrict__ W4,
    int* __restrict__ Z /* CNT, 8192 ints */)
{
    int tid = threadIdx.x;
    if (blockIdx.x >= CONV1_BLOCKS) {
        // ---------------- prep region (R9/R12-proven) ----------------
        int gtid = (blockIdx.x - CONV1_BLOCKS) * 256 + tid;
        int wid  = gtid >> 6;
        int lane = gtid & 63;
        if (wid < 576) {
            int oc = wid / 9, t = wid - oc * 9;
            float v = (lane < 32) ? w2[oc * 288 + lane * 9 + t] : -1.0f;
            uint64_t m = __ballot(v >= 0.0f);
            if (lane == 0) W2[wid] = (uint32_t)m;
        } else if (wid < 1728) {
            int i = wid - 576;
            int oc = i / 9, t = i - oc * 9;
            float v = w3[oc * 576 + lane * 9 + t];
            uint64_t m = __ballot(v >= 0.0f);
            if (lane == 0) W3[i] = m;
        } else if (wid < 6336) {
            int i = wid - 1728;
            int oc = i / 18, rem = i - oc * 18;
            int t = rem >> 1, h = rem & 1;
            float v = w4[oc * 1152 + (h * 64 + lane) * 9 + t];
            uint64_t m = __ballot(v >= 0.0f);
            if (lane == 0) W4[i] = m;
        } else if (wid < 6344) {
            int c = (wid - 6336) * 64 + lane;   // 0..511
            if (c < 64) {
                T2[c] = find_T(288, bnf(g2[c], b2[c], m2[c], v2[c]));
            } else if (c < 192) {
                int cc = c - 64;
                T3[cc] = find_T(576, bnf(g3[cc], b3[cc], m3[cc], v3[cc]));
            } else if (c < 448) {
                int cc = c - 192;
                T4[cc] = find_T(1152, bnf(g4[cc], b4[cc], m4[cc], v4[cc]));
            }
        } else {
            int zi = gtid - 406016;
            if (zi < 8192) Z[zi] = 0;
        }
        return;
    }

    // ---------------- conv1: 4 px/thread, oc-group-tiled accumulators ----------------
    __shared__ float  wl[27 * 32];   // [k][oc]
    __shared__ float2 s1[32];
    for (int i = tid; i < 864; i += 256) {
        int k = i >> 5, oc = i & 31;
        wl[i] = w1[oc * 27 + k];
    }
    if (tid < 32) s1[tid] = bnf(g1[tid], b1[tid], m1[tid], v1[tid]);
    __syncthreads();

    int q  = blockIdx.x * 256 + tid;    // quad id: [b][y][xq]
    int xq = q % 56;
    int t  = q / 56;
    int y  = t % 224;
    int b  = t / 224;
    int xc = xq * 4;

    const float* xb = x + (size_t)b * 150528;
    bool interior = ((unsigned)(y - 1) < 222u) && ((unsigned)(xq - 1) < 54u);

    // input window: xin[row=ic*3+ky][c], cols xc-1..xc+4
    float xin[9][6];
    #pragma unroll
    for (int ic = 0; ic < 3; ic++)
        #pragma unroll
        for (int ky = 0; ky < 3; ky++) {
            int iy = y - 1 + ky;
            const float* rp = xb + ic * 50176 + iy * 224 + (xc - 1);
            float* xr = xin[ic * 3 + ky];
            if (interior) {
                #pragma unroll
                for (int c = 0; c < 6; c++) xr[c] = rp[c];
            } else {
                #pragma unroll
                for (int c = 0; c < 6; c++) {
                    int ix = xc - 1 + c;
                    xr[c] = ((unsigned)iy < 224u && (unsigned)ix < 224u) ? rp[c] : 0.0f;
                }
            }
        }

    const float4* wl4 = (const float4*)wl;
    uint32_t bits0 = 0, bits1 = 0, bits2 = 0, bits3 = 0;

    #pragma unroll 1                     // keep og live-set small: acc[4][4] only
    for (int og = 0; og < 8; og++) {
        float acc[4][4];                 // [px][oc-in-group]
        #pragma unroll
        for (int px = 0; px < 4; px++)
            #pragma unroll
            for (int j = 0; j < 4; j++) acc[px][j] = 0.0f;

        #pragma unroll
        for (int k = 0; k < 27; k++) {   // k-ascending per acc chain: bit-exact
            float4 w = wl4[k * 8 + og];
            int row = k / 3, kx = k % 3;
            #pragma unroll
            for (int px = 0; px < 4; px++) {
                float a = xin[row][kx + px];
                acc[px][0] = fmaf(a, w.x, acc[px][0]);
                acc[px][1] = fmaf(a, w.y, acc[px][1]);
                acc[px][2] = fmaf(a, w.z, acc[px][2]);
                acc[px][3] = fmaf(a, w.w, acc[px][3]);
            }
        }

        #pragma unroll
        for (int j = 0; j < 4; j++) {
            float2 p = s1[og * 4 + j];
            int sh = og * 4 + j;
            bits0 |= (uint32_t)bnpos(acc[0][j], p) << sh;
            bits1 |= (uint32_t)bnpos(acc[1][j], p) << sh;
            bits2 |= (uint32_t)bnpos(acc[2][j], p) << sh;
            bits3 |= (uint32_t)bnpos(acc[3][j], p) << sh;
        }
    }

    uint4* dst = (uint4*)(A1 + (size_t)b * 50176 + y * 224 + xc);  // 16B aligned
    *dst = make_uint4(bits0, bits1, bits2, bits3);
}

// ======== conv2 (R9-proven, verbatim) ========
template<unsigned VM>
static __device__ __forceinline__ bool pred2(const uint32_t (&w)[3][9], int j,
                                             const uint32_t (&wr)[9], int T) {
    int pc = 0;
    #pragma unroll
    for (int ky = 0; ky < 3; ky++)
        #pragma unroll
        for (int kx = 0; kx < 3; kx++) {
            int ti = ky * 3 + kx;
            if (VM & (1u << ti)) pc += __popc(w[ky][2 * j + kx] ^ wr[ti]);
        }
    constexpr int nv = __builtin_popcount(VM);
    return pc <= ((32 * nv - T) >> 1);
}

template<unsigned VM0, unsigned VM>
static __device__ __forceinline__ void group2(const uint32_t* lrow, int g,
        const uint32_t (&wr)[9], int T, uint64_t* dst, int lane) {
    uint32_t win[3][9];
    int c0 = 8 * g;
    #pragma unroll
    for (int r = 0; r < 3; r++) {
        const uint32_t* rp = lrow + r * C2_LW + c0;
        uint4 a = *(const uint4*)(rp);
        uint4 b = *(const uint4*)(rp + 4);
        win[r][0] = a.x; win[r][1] = a.y; win[r][2] = a.z; win[r][3] = a.w;
        win[r][4] = b.x; win[r][5] = b.y; win[r][6] = b.z; win[r][7] = b.w;
        win[r][8] = rp[8];
    }
    uint64_t b0 = __ballot(pred2<VM0>(win, 0, wr, T));
    uint64_t b1 = __ballot(pred2<VM >(win, 1, wr, T));
    uint64_t b2 = __ballot(pred2<VM >(win, 2, wr, T));
    uint64_t b3 = __ballot(pred2<VM >(win, 3, wr, T));
    if (lane == 0) {
        ulonglong2* d = (ulonglong2*)(dst + 4 * g);
        d[0] = make_ulonglong2(b0, b1);
        d[1] = make_ulonglong2(b2, b3);
    }
}

__global__ __launch_bounds__(256) void k_conv2(
    const uint32_t* __restrict__ A1, const uint32_t* __restrict__ W2g,
    const int* __restrict__ T2, uint64_t* __restrict__ A2)
{
    __shared__ __align__(16) uint32_t lds[9 * C2_LW];
    int bi = blockIdx.x;
    int b = bi / 56, rem = bi % 56;
    int oyq = rem >> 1, h = rem & 1;
    int xs = h * 56;
    int tid = threadIdx.x;
    const uint32_t* ap = A1 + (size_t)b * 50176;
    for (int i = tid; i < 9 * C2_LW; i += 256) {
        int r = i / C2_LW, c = i - r * C2_LW;
        int iy = oyq * 8 - 1 + r, ix = 2 * xs - 1 + c;
        uint32_t v = 0;
        if ((unsigned)iy < 224u && (unsigned)ix < 224u) v = ap[iy * 224 + ix];
        lds[i] = v;
    }
    __syncthreads();

    int w = tid >> 6, lane = tid & 63;
    int oy = oyq * 4 + w;
    uint32_t wr[9];
    #pragma unroll
    for (int ti = 0; ti < 9; ti++) wr[ti] = W2g[lane * 9 + ti];
    int T = T2[lane];
    const uint32_t* lrow = lds + 2 * w * C2_LW;
    uint64_t* dst = A2 + (size_t)b * 12544 + oy * 112 + xs;
    bool left = (xs == 0);

    if (oy == 0) {
        if (left) group2<0x1B0, 0x1F8>(lrow, 0, wr, T, dst, lane);
        else      group2<0x1F8, 0x1F8>(lrow, 0, wr, T, dst, lane);
        for (int g = 1; g < 14; g++) group2<0x1F8, 0x1F8>(lrow, g, wr, T, dst, lane);
    } else {
        if (left) group2<0x1B6, 0x1FF>(lrow, 0, wr, T, dst, lane);
        else      group2<0x1FF, 0x1FF>(lrow, 0, wr, T, dst, lane);
        for (int g = 1; g < 14; g++) group2<0x1FF, 0x1FF>(lrow, g, wr, T, dst, lane);
    }
}

// ======== conv3 (R9-proven, verbatim): A2 -> A3 planar [2][32][56][56] ========
#define C3_LW 58
template<unsigned VM>
static __device__ __forceinline__ bool pred3(const uint64_t (&w)[3][9], int j,
                                             const uint64_t (&wr)[9], int T) {
    int pc = 0;
    #pragma unroll
    for (int ky = 0; ky < 3; ky++)
        #pragma unroll
        for (int kx = 0; kx < 3; kx++) {
            int ti = ky * 3 + kx;
            if (VM & (1u << ti)) pc += __popcll(w[ky][2 * j + kx] ^ wr[ti]);
        }
    constexpr int nv = __builtin_popcount(VM);
    return pc <= ((64 * nv - T) >> 1);
}

template<unsigned VM0, unsigned VM>
static __device__ __forceinline__ void group3(const uint64_t* lrow, int g,
        const uint64_t (&wr)[9], int T, uint64_t* dst, int lane) {
    uint64_t win[3][9];
    int c0 = 8 * g;
    #pragma unroll
    for (int r = 0; r < 3; r++) {
        const uint64_t* rp = lrow + r * C3_LW + c0;
        ulonglong2 a0 = *(const ulonglong2*)(rp);
        ulonglong2 a1 = *(const ulonglong2*)(rp + 2);
        ulonglong2 a2 = *(const ulonglong2*)(rp + 4);
        ulonglong2 a3 = *(const ulonglong2*)(rp + 6);
        win[r][0] = a0.x; win[r][1] = a0.y; win[r][2] = a1.x; win[r][3] = a1.y;
        win[r][4] = a2.x; win[r][5] = a2.y; win[r][6] = a3.x; win[r][7] = a3.y;
        win[r][8] = rp[8];
    }
    uint64_t b0 = __ballot(pred3<VM0>(win, 0, wr, T));
    uint64_t b1 = __ballot(pred3<VM >(win, 1, wr, T));
    uint64_t b2 = __ballot(pred3<VM >(win, 2, wr, T));
    uint64_t b3 = __ballot(pred3<VM >(win, 3, wr, T));
    if (lane == 0) {
        ulonglong2* d = (ulonglong2*)(dst + 4 * g);
        d[0] = make_ulonglong2(b0, b1);
        d[1] = make_ulonglong2(b2, b3);
    }
}

__global__ __launch_bounds__(256) void k_conv3(
    const uint64_t* __restrict__ A2, const uint64_t* __restrict__ W3g,
    const int* __restrict__ T3, uint64_t* __restrict__ A3)
{
    __shared__ __align__(16) uint64_t lds[5 * C3_LW];
    int bi = blockIdx.x;
    int b = bi / 56, rem = bi % 56;
    int oyp = rem >> 1, h = rem & 1;
    int xs = h * 28;
    int tid = threadIdx.x;
    const uint64_t* ap = A2 + (size_t)b * 12544;
    for (int i = tid; i < 5 * C3_LW; i += 256) {
        int r = i / C3_LW, c = i - r * C3_LW;
        int iy = oyp * 4 - 1 + r, ix = 2 * xs - 1 + c;
        uint64_t v = 0;
        if ((unsigned)iy < 112u && (unsigned)ix < 112u) v = ap[iy * 112 + ix];
        lds[i] = v;
    }
    __syncthreads();

    int w = tid >> 6, lane = tid & 63;
    int oy = oyp * 2 + (w >> 1);
    int g  = w & 1;
    int oc = g * 64 + lane;
    uint64_t wr[9];
    #pragma unroll
    for (int ti = 0; ti < 9; ti++) wr[ti] = W3g[oc * 9 + ti];
    int T = T3[oc];
    const uint64_t* lrow = lds + 2 * (w >> 1) * C3_LW;
    uint64_t* dst = A3 + (size_t)g * 100352 + (size_t)b * 3136 + oy * 56 + xs;
    bool left = (xs == 0);

    if (oy == 0) {
        if (left) group3<0x1B0, 0x1F8>(lrow, 0, wr, T, dst, lane);
        else      group3<0x1F8, 0x1F8>(lrow, 0, wr, T, dst, lane);
        for (int gg = 1; gg < 7; gg++) group3<0x1F8, 0x1F8>(lrow, gg, wr, T, dst, lane);
    } else {
        if (left) group3<0x1B6, 0x1FF>(lrow, 0, wr, T, dst, lane);
        else      group3<0x1FF, 0x1FF>(lrow, 0, wr, T, dst, lane);
        for (int gg = 1; gg < 7; gg++) group3<0x1FF, 0x1FF>(lrow, gg, wr, T, dst, lane);
    }
}

// ======== conv4 -> CNT (R9-proven, verbatim) ========
template<unsigned VM>
static __device__ __forceinline__ bool pred4(const uint64_t (&w0)[3][5],
                                             const uint64_t (&w1)[3][5], int j,
                                             const ulonglong2 (&wr)[9], int T) {
    int pc = 0;
    #pragma unroll
    for (int ky = 0; ky < 3; ky++)
        #pragma unroll
        for (int kx = 0; kx < 3; kx++) {
            int ti = ky * 3 + kx;
            if (VM & (1u << ti)) {
                pc += __popcll(w0[ky][2 * j + kx] ^ wr[ti].x);
                pc += __popcll(w1[ky][2 * j + kx] ^ wr[ti].y);
            }
        }
    constexpr int nv = __builtin_popcount(VM);
    return pc <= ((128 * nv - T) >> 1);
}

template<unsigned VM0, unsigned VM>
static __device__ __forceinline__ int group4c(const uint64_t* ldsb, int g,
        const ulonglong2 (&wr)[9], int T) {
    uint64_t w0[3][5], w1[3][5];
    int c0 = 4 * g;
    #pragma unroll
    for (int r = 0; r < 3; r++) {
        const uint64_t* rp0 = ldsb + r * 30 + c0;
        const uint64_t* rp1 = ldsb + (3 + r) * 30 + c0;
        ulonglong2 a0 = *(const ulonglong2*)(rp0);
        ulonglong2 a1 = *(const ulonglong2*)(rp0 + 2);
        w0[r][0] = a0.x; w0[r][1] = a0.y; w0[r][2] = a1.x; w0[r][3] = a1.y;
        w0[r][4] = rp0[4];
        ulonglong2 b0 = *(const ulonglong2*)(rp1);
        ulonglong2 b1 = *(const ulonglong2*)(rp1 + 2);
        w1[r][0] = b0.x; w1[r][1] = b0.y; w1[r][2] = b1.x; w1[r][3] = b1.y;
        w1[r][4] = rp1[4];
    }
    int c = 0;
    c += pred4<VM0>(w0, w1, 0, wr, T) ? 1 : 0;
    c += pred4<VM >(w0, w1, 1, wr, T) ? 1 : 0;
    return c;
}

__global__ __launch_bounds__(256) void k_conv4(
    const uint64_t* __restrict__ A3, const uint64_t* __restrict__ W4g,
    const int* __restrict__ T4, int* __restrict__ CNT)
{
    __shared__ __align__(16) uint64_t lds[2 * 3 * 30];
    int bi = blockIdx.x;
    int b = bi / 56, rem = bi % 56;
    int oy = rem >> 1, h = rem & 1;
    int tid = threadIdx.x;
    const uint64_t* ap = A3 + (size_t)b * 3136;
    for (int i = tid; i < 174; i += 256) {
        int p = i / 87, j = i - p * 87;
        int r = j / 29, c = j - r * 29;
        int iy = 2 * oy - 1 + r, ix = 2 * h * 14 - 1 + c;
        uint64_t v = 0;
        if ((unsigned)iy < 56u && (unsigned)ix < 56u)
            v = ap[(size_t)p * 100352 + iy * 56 + ix];
        lds[(p * 3 + r) * 30 + c] = v;
    }
    __syncthreads();

    int w = tid >> 6, lane = tid & 63;
    int oc = w * 64 + lane;
    ulonglong2 wr[9];
    const ulonglong2* wp = (const ulonglong2*)(W4g + oc * 18);
    #pragma unroll
    for (int ti = 0; ti < 9; ti++) wr[ti] = wp[ti];
    int T = T4[oc];
    bool left = (h == 0);

    int cnt = 0;
    if (oy == 0) {
        if (left) cnt += group4c<0x1B0, 0x1F8>(lds, 0, wr, T);
        else      cnt += group4c<0x1F8, 0x1F8>(lds, 0, wr, T);
        for (int g = 1; g < 7; g++) cnt += group4c<0x1F8, 0x1F8>(lds, g, wr, T);
    } else {
        if (left) cnt += group4c<0x1B6, 0x1FF>(lds, 0, wr, T);
        else      cnt += group4c<0x1FF, 0x1FF>(lds, 0, wr, T);
        for (int g = 1; g < 7; g++) cnt += group4c<0x1FF, 0x1FF>(lds, g, wr, T);
    }
    atomicAdd(&CNT[b * 256 + oc], cnt);
}

// ---------------- tail: CNT -> mean -> fc (R9-proven) ----------------
__global__ __launch_bounds__(256) void k_tail(
    const int* __restrict__ CNT, const float* __restrict__ fcw,
    const float* __restrict__ fcb, float* __restrict__ out)
{
    int b = blockIdx.x;
    int c = threadIdx.x;
    int cnt = CNT[b * 256 + c];
    double mean = (2.0 * (double)cnt - 784.0) * (1.0 / 784.0);

    __shared__ double r0[256], r1[256];
    r0[c] = (double)fcw[c]       * mean;
    r1[c] = (double)fcw[256 + c] * mean;
    __syncthreads();
    for (int s = 128; s > 0; s >>= 1) {
        if (c < s) { r0[c] += r0[c + s]; r1[c] += r1[c + s]; }
        __syncthreads();
    }
    if (c == 0) {
        out[b * 2 + 0] = (float)(r0[0] + (double)fcb[0]);
        out[b * 2 + 1] = (float)(r1[0] + (double)fcb[1]);
    }
}

extern "C" void kernel_launch(void* const* d_in, const int* in_sizes, int n_in,
                              void* d_out, int out_size, void* d_ws, size_t ws_size,
                              hipStream_t stream) {
    const float* x   = (const float*)d_in[0];
    const float* w1  = (const float*)d_in[1];
    const float* w2  = (const float*)d_in[2];
    const float* w3  = (const float*)d_in[3];
    const float* w4  = (const float*)d_in[4];
    const float* g1 = (const float*)d_in[5],  *b1 = (const float*)d_in[6],
               * m1 = (const float*)d_in[7],  *v1 = (const float*)d_in[8];
    const float* g2 = (const float*)d_in[9],  *b2 = (const float*)d_in[10],
               * m2 = (const float*)d_in[11], *v2 = (const float*)d_in[12];
    const float* g3 = (const float*)d_in[13], *b3 = (const float*)d_in[14],
               * m3 = (const float*)d_in[15], *v3 = (const float*)d_in[16];
    const float* g4 = (const float*)d_in[17], *b4 = (const float*)d_in[18],
               * m4 = (const float*)d_in[19], *v4 = (const float*)d_in[20];
    const float* fcw = (const float*)d_in[21];
    const float* fcb = (const float*)d_in[22];
    float* out = (float*)d_out;

    char* ws = (char*)d_ws;
    int*      T2  = (int*)(ws + OFF_T2);
    int*      T3  = (int*)(ws + OFF_T3);
    int*      T4  = (int*)(ws + OFF_T4);
    uint32_t* W2  = (uint32_t*)(ws + OFF_W2);
    uint64_t* W3  = (uint64_t*)(ws + OFF_W3);
    uint64_t* W4  = (uint64_t*)(ws + OFF_W4);
    uint32_t* A1  = (uint32_t*)(ws + OFF_A1);
    uint64_t* A2  = (uint64_t*)(ws + OFF_A2);
    uint64_t* A3  = (uint64_t*)(ws + OFF_A3);
    int*      CNT = (int*)(ws + OFF_CNT);

    hipLaunchKernelGGL(k_front, dim3(CONV1_BLOCKS + PREP_BLOCKS), dim3(256), 0, stream,
                       x, w1, g1, b1, m1, v1, w2, w3, w4,
                       g2, b2, m2, v2, g3, b3, m3, v3, g4, b4, m4, v4,
                       A1, T2, T3, T4, W2, W3, W4, CNT);
    hipLaunchKernelGGL(k_conv2, dim3(1792), dim3(256), 0, stream, A1, W2, T2, A2);
    hipLaunchKernelGGL(k_conv3, dim3(1792), dim3(256), 0, stream, A2, W3, T3, A3);
    hipLaunchKernelGGL(k_conv4, dim3(1792), dim3(256), 0, stream, A3, W4, T4, CNT);
    hipLaunchKernelGGL(k_tail,  dim3(32),   dim3(256), 0, stream, CNT, fcw, fcb, out);
}